// Round 11
// baseline (163.296 us; speedup 1.0000x reference)
//
#include <hip/hip_runtime.h>
#include <hip/hip_bf16.h>

#define NEG_INF (-3.402823466e+38f)
#define SCALE 0.17677669529663689f  // 1/sqrt(32)

typedef __attribute__((ext_vector_type(8))) short bf16x8;
typedef __attribute__((ext_vector_type(4))) float f32x4;
typedef __attribute__((ext_vector_type(4))) unsigned short u16x4;
typedef __attribute__((ext_vector_type(4))) unsigned int u32x4;

__device__ __forceinline__ unsigned short f2bf(float f) {
  union { float f; unsigned u; } v; v.f = f;
  unsigned r = v.u + 0x7fffu + ((v.u >> 16) & 1u);
  return (unsigned short)(r >> 16);
}

// packed pair via compiler cvt_pk (RNE, matches f2bf)
__device__ __forceinline__ unsigned pack2(float lo, float hi) {
  __hip_bfloat162 h2 = __float22bfloat162_rn(make_float2(lo, hi));
  return *reinterpret_cast<unsigned*>(&h2);
}

__device__ __forceinline__ bf16x8 pack_bf8(const float* __restrict__ p) {
  float4 a = *(const float4*)p;
  float4 b = *(const float4*)(p + 4);
  u32x4 u;
  u[0] = pack2(a.x, a.y); u[1] = pack2(a.z, a.w);
  u[2] = pack2(b.x, b.y); u[3] = pack2(b.z, b.w);
  return __builtin_bit_cast(bf16x8, u);
}

// Precompute fused weight products (bf16):
//  MT[h][i][j] = M_h[j][i] = sum_d Wq[h*32+d][j] * Wk[h*32+d][i]
//  WB[o][h*128+i]          = sum_d Wo[o][h*32+d] * Wv[h*32+d][i]
__global__ __launch_bounds__(256) void fuse_weights(
    const float* __restrict__ wq, const float* __restrict__ wk,
    const float* __restrict__ wv, const float* __restrict__ wo,
    unsigned short* __restrict__ MT, unsigned short* __restrict__ WB) {
  const int w = (blockIdx.x * 256 + threadIdx.x) >> 6;  // wave id 0..255
  const int lane = threadIdx.x & 63;
  const int lr = lane & 15, lk = lane >> 4;
  const int h = w >> 6, t2 = w & 63, jt = t2 >> 3, it = t2 & 7;

  bf16x8 a, b;
#pragma unroll
  for (int j = 0; j < 8; ++j) {
    a[j] = (short)f2bf(wq[(h * 32 + lk * 8 + j) * 128 + jt * 16 + lr]);
    b[j] = (short)f2bf(wk[(h * 32 + lk * 8 + j) * 128 + it * 16 + lr]);
  }
  f32x4 c = (f32x4){0.f, 0.f, 0.f, 0.f};
  c = __builtin_amdgcn_mfma_f32_16x16x32_bf16(a, b, c, 0, 0, 0);
#pragma unroll
  for (int r = 0; r < 4; ++r)
    MT[h * 16384 + (it * 16 + lr) * 128 + jt * 16 + lk * 4 + r] = f2bf(c[r]);

  bf16x8 a2 = pack_bf8(wo + (jt * 16 + lr) * 128 + h * 32 + lk * 8);
  bf16x8 b2;
#pragma unroll
  for (int j = 0; j < 8; ++j)
    b2[j] = (short)f2bf(wv[(h * 32 + lk * 8 + j) * 128 + it * 16 + lr]);
  f32x4 c2 = (f32x4){0.f, 0.f, 0.f, 0.f};
  c2 = __builtin_amdgcn_mfma_f32_16x16x32_bf16(a2, b2, c2, 0, 0, 0);
#pragma unroll
  for (int r = 0; r < 4; ++r)
    WB[(size_t)(jt * 16 + lk * 4 + r) * 512 + h * 128 + it * 16 + lr] = f2bf(c2[r]);
}

// WQ[n][h*128+i] = sum_j hV[n][j] * M_h[j][i]; all 4 heads per block (h-loop).
__global__ __launch_bounds__(256) void gemm_wq(
    const float* __restrict__ X, const unsigned short* __restrict__ MT,
    unsigned short* __restrict__ WQb, int M) {
  __shared__ unsigned short Wl[128 * 136];
  const int wave = threadIdx.x >> 6, lane = threadIdx.x & 63;
  const int lr = lane & 15, lk = lane >> 4;
  const int row0 = blockIdx.x * 64 + wave * 16;
  const int arow = row0 + lr;

  bf16x8 af[4];
  if (arow < M) {
    const float* xr = X + (size_t)arow * 128;
#pragma unroll
    for (int kk = 0; kk < 4; ++kk) af[kk] = pack_bf8(xr + kk * 32 + lk * 8);
  } else {
#pragma unroll
    for (int kk = 0; kk < 4; ++kk) af[kk] = (bf16x8)(short)0;
  }

  for (int h = 0; h < 4; ++h) {
    __syncthreads();
    const unsigned short* Wsrc = MT + (size_t)h * 16384;
    for (int idx = threadIdx.x; idx < 2048; idx += 256) {
      int row = idx >> 4, col = (idx & 15) * 8;
      *(bf16x8*)&Wl[row * 136 + col] = *(const bf16x8*)(Wsrc + row * 128 + col);
    }
    __syncthreads();

    f32x4 acc[8];
#pragma unroll
    for (int ct = 0; ct < 8; ++ct) acc[ct] = (f32x4){0.f, 0.f, 0.f, 0.f};
#pragma unroll
    for (int kk = 0; kk < 4; ++kk)
#pragma unroll
      for (int ct = 0; ct < 8; ++ct) {
        bf16x8 b = *(const bf16x8*)&Wl[(ct * 16 + lr) * 136 + kk * 32 + lk * 8];
        acc[ct] = __builtin_amdgcn_mfma_f32_16x16x32_bf16(af[kk], b, acc[ct], 0, 0, 0);
      }

#pragma unroll
    for (int ct = 0; ct < 8; ++ct)
#pragma unroll
      for (int r = 0; r < 4; ++r) {
        int row = row0 + lk * 4 + r;
        if (row < M)
          WQb[(size_t)row * 512 + h * 128 + ct * 16 + lr] = f2bf(acc[ct][r]);
      }
  }
}

// Fused: logits -> softmax -> aE. 4 waves/block; each wave loops over 4
// consecutive nodes (grid-stride style, 1875 blocks instead of 7500 — G11:
// remove block launch/drain churn for memory-bound kernels). Per-wave DS
// ordering makes El/attL reuse across iterations safe without barriers.
// E tile loaded in TWO 16-row halves (32 VGPR each, peak pressure < 128).
// XOR-swizzled LDS copy, pitch 128: block b of row k at b ^ (((k>>3)&3)<<1).
__global__ __launch_bounds__(256, 4) void neigh_aE(
    const float* __restrict__ hE, const int* __restrict__ mask,
    const unsigned short* __restrict__ WQb, unsigned short* __restrict__ aEb,
    int N) {
  __shared__ unsigned short Elds[4][32 * 128];  // 8 KB per wave
  __shared__ unsigned short attL[4][128];       // att bf16 [h][k] per wave

  const int wave = threadIdx.x >> 6, lane = threadIdx.x & 63;
  const int lr = lane & 15, lk = lane >> 4;
  unsigned short* El = Elds[wave];
  unsigned short* at = attL[wave];
  const int wid = blockIdx.x * 4 + wave;

#pragma unroll 1
  for (int it = 0; it < 4; ++it) {
    const int n = wid * 4 + it;
    if (n >= N) break;

    const float* E = hE + (size_t)n * 4096;

    // ---- half A: rows 0-15 (32 VGPRs of raw) + small operands in flight ----
    float4 rawA[8];
#pragma unroll
    for (int q = 0; q < 4; ++q) {
      const float* p = E + lr * 128 + q * 32 + lk * 8;
      rawA[q * 2] = *(const float4*)p;
      rawA[q * 2 + 1] = *(const float4*)(p + 4);
    }
    bf16x8 bq[4];
#pragma unroll
    for (int kk = 0; kk < 4; ++kk)
      bq[kk] = *(const bf16x8*)(WQb + (size_t)n * 512 + (lr & 3) * 128 + kk * 32 + lk * 8);
    const int4 m0 = *(const int4*)(mask + (size_t)n * 32 + lk * 4);
    const int4 m1 = *(const int4*)(mask + (size_t)n * 32 + 16 + lk * 4);

    bf16x8 af0[4];
#pragma unroll
    for (int q = 0; q < 4; ++q) {
      float4 a = rawA[q * 2], b = rawA[q * 2 + 1];
      u32x4 u;
      u[0] = pack2(a.x, a.y); u[1] = pack2(a.z, a.w);
      u[2] = pack2(b.x, b.y); u[3] = pack2(b.z, b.w);
      bf16x8 t = __builtin_bit_cast(bf16x8, u);
      af0[q] = t;
      const int bswz = (q * 4 + lk) ^ ((lr >> 3) << 1);
      *(bf16x8*)&El[lr * 128 + bswz * 8] = t;
    }

    __builtin_amdgcn_sched_barrier(0);

    // ---- half B: rows 16-31 (reuses the raw register budget) ----
    float4 rawB[8];
#pragma unroll
    for (int q = 0; q < 4; ++q) {
      const float* p = E + (16 + lr) * 128 + q * 32 + lk * 8;
      rawB[q * 2] = *(const float4*)p;
      rawB[q * 2 + 1] = *(const float4*)(p + 4);
    }
    bf16x8 af1[4];
#pragma unroll
    for (int q = 0; q < 4; ++q) {
      float4 a = rawB[q * 2], b = rawB[q * 2 + 1];
      u32x4 u;
      u[0] = pack2(a.x, a.y); u[1] = pack2(a.z, a.w);
      u[2] = pack2(b.x, b.y); u[3] = pack2(b.z, b.w);
      bf16x8 t = __builtin_bit_cast(bf16x8, u);
      af1[q] = t;
      const int bswz = (q * 4 + lk) ^ (((2 + (lr >> 3)) & 3) << 1);
      *(bf16x8*)&El[(16 + lr) * 128 + bswz * 8] = t;
    }

    // logits D[k][h]: lane holds k = rt*16 + lk*4 + r, col = head lr&3
    f32x4 c0 = (f32x4){0.f, 0.f, 0.f, 0.f};
    f32x4 c1 = (f32x4){0.f, 0.f, 0.f, 0.f};
#pragma unroll
    for (int kk = 0; kk < 4; ++kk) {
      c0 = __builtin_amdgcn_mfma_f32_16x16x32_bf16(af0[kk], bq[kk], c0, 0, 0, 0);
      c1 = __builtin_amdgcn_mfma_f32_16x16x32_bf16(af1[kk], bq[kk], c1, 0, 0, 0);
    }

    // masked softmax over k
    float l[2][4];
    l[0][0] = m0.x ? c0[0] * SCALE : NEG_INF;
    l[0][1] = m0.y ? c0[1] * SCALE : NEG_INF;
    l[0][2] = m0.z ? c0[2] * SCALE : NEG_INF;
    l[0][3] = m0.w ? c0[3] * SCALE : NEG_INF;
    l[1][0] = m1.x ? c1[0] * SCALE : NEG_INF;
    l[1][1] = m1.y ? c1[1] * SCALE : NEG_INF;
    l[1][2] = m1.z ? c1[2] * SCALE : NEG_INF;
    l[1][3] = m1.w ? c1[3] * SCALE : NEG_INF;

    float mx = l[0][0];
#pragma unroll
    for (int rt = 0; rt < 2; ++rt)
#pragma unroll
      for (int r = 0; r < 4; ++r) mx = fmaxf(mx, l[rt][r]);
    mx = fmaxf(mx, __shfl_xor(mx, 16, 64));
    mx = fmaxf(mx, __shfl_xor(mx, 32, 64));

    float e[2][4];
    float sum = 0.f;
#pragma unroll
    for (int rt = 0; rt < 2; ++rt)
#pragma unroll
      for (int r = 0; r < 4; ++r) { e[rt][r] = __expf(l[rt][r] - mx); sum += e[rt][r]; }
    sum += __shfl_xor(sum, 16, 64);
    sum += __shfl_xor(sum, 32, 64);
    const float inv = 1.0f / sum;

    if (lr < 4) {  // att[h=lr][k] bf16
      u16x4 p0, p1;
      p0[0] = f2bf(m0.x ? e[0][0] * inv : 0.f);
      p0[1] = f2bf(m0.y ? e[0][1] * inv : 0.f);
      p0[2] = f2bf(m0.z ? e[0][2] * inv : 0.f);
      p0[3] = f2bf(m0.w ? e[0][3] * inv : 0.f);
      p1[0] = f2bf(m1.x ? e[1][0] * inv : 0.f);
      p1[1] = f2bf(m1.y ? e[1][1] * inv : 0.f);
      p1[2] = f2bf(m1.z ? e[1][2] * inv : 0.f);
      p1[3] = f2bf(m1.w ? e[1][3] * inv : 0.f);
      *(u16x4*)&at[lr * 32 + lk * 4] = p0;
      *(u16x4*)&at[lr * 32 + 16 + lk * 4] = p1;
    }

    // aE: D[m][i] = sum_k att[m&3][k] E[k][ct*16+i]
    bf16x8 attA = *(const bf16x8*)&at[(lr & 3) * 32 + lk * 8];
    const int e0 = lr & 7;
#pragma unroll
    for (int ct = 0; ct < 8; ++ct) {
      const int blk = (ct * 2 + (lr >> 3)) ^ (lk << 1);
      bf16x8 bE;
#pragma unroll
      for (int j = 0; j < 8; ++j)
        bE[j] = (short)El[(lk * 8 + j) * 128 + blk * 8 + e0];
      f32x4 acc = (f32x4){0.f, 0.f, 0.f, 0.f};
      acc = __builtin_amdgcn_mfma_f32_16x16x32_bf16(attA, bE, acc, 0, 0, 0);
      // reg r holds head r (duplicated across lk); lane stores head = lk
      float v = (lk == 0) ? acc[0] : (lk == 1) ? acc[1] : (lk == 2) ? acc[2] : acc[3];
      aEb[(size_t)n * 512 + lk * 128 + ct * 16 + lr] = f2bf(v);
    }
  }
}

// out[n][o] = sum_{h,i} aE[n][h*128+i] * WB[o][h*128+i]
__global__ __launch_bounds__(256) void gemm_out(
    const unsigned short* __restrict__ aEb, const unsigned short* __restrict__ WB,
    float* __restrict__ Y, int M) {
  __shared__ unsigned short Wl[128 * 136];
  const int wave = threadIdx.x >> 6, lane = threadIdx.x & 63;
  const int lr = lane & 15, lk = lane >> 4;
  const int row0 = blockIdx.x * 64 + wave * 16;
  const int arow = row0 + lr;

  f32x4 acc[8];
#pragma unroll
  for (int ct = 0; ct < 8; ++ct) acc[ct] = (f32x4){0.f, 0.f, 0.f, 0.f};

  for (int h = 0; h < 4; ++h) {
    __syncthreads();
    for (int idx = threadIdx.x; idx < 2048; idx += 256) {
      int row = idx >> 4, col = (idx & 15) * 8;
      *(bf16x8*)&Wl[row * 136 + col] = *(const bf16x8*)(WB + (size_t)row * 512 + h * 128 + col);
    }
    __syncthreads();

    bf16x8 af[4];
    if (arow < M) {
#pragma unroll
      for (int kk = 0; kk < 4; ++kk)
        af[kk] = *(const bf16x8*)(aEb + (size_t)arow * 512 + h * 128 + kk * 32 + lk * 8);
    } else {
#pragma unroll
      for (int kk = 0; kk < 4; ++kk) af[kk] = (bf16x8)(short)0;
    }
#pragma unroll
    for (int kk = 0; kk < 4; ++kk)
#pragma unroll
      for (int ct = 0; ct < 8; ++ct) {
        bf16x8 b = *(const bf16x8*)&Wl[(ct * 16 + lr) * 136 + kk * 32 + lk * 8];
        acc[ct] = __builtin_amdgcn_mfma_f32_16x16x32_bf16(af[kk], b, acc[ct], 0, 0, 0);
      }
  }

#pragma unroll
  for (int ct = 0; ct < 8; ++ct)
#pragma unroll
    for (int r = 0; r < 4; ++r) {
      int row = row0 + lk * 4 + r;
      if (row < M) Y[(size_t)row * 128 + ct * 16 + lr] = acc[ct][r];
    }
}

extern "C" void kernel_launch(void* const* d_in, const int* in_sizes, int n_in,
                              void* d_out, int out_size, void* d_ws, size_t ws_size,
                              hipStream_t stream) {
  const float* hV = (const float*)d_in[0];
  const float* hE = (const float*)d_in[1];
  const int* mask = (const int*)d_in[2];
  const float* Wq = (const float*)d_in[3];
  const float* Wk = (const float*)d_in[4];
  const float* Wv = (const float*)d_in[5];
  const float* Wo = (const float*)d_in[6];
  float* out = (float*)d_out;
  const int N = in_sizes[0] / 128;  // 30000

  char* ws = (char*)d_ws;
  unsigned short* MT = (unsigned short*)(ws);            // 4*128*128*2 = 128 KB
  unsigned short* WB = (unsigned short*)(ws + 131072);   // 128*512*2  = 128 KB
  unsigned short* WQb = (unsigned short*)(ws + 262144);               // N*512 bf16
  unsigned short* aEb = (unsigned short*)(ws + 262144 + (size_t)N * 1024);

  fuse_weights<<<64, 256, 0, stream>>>(Wq, Wk, Wv, Wo, MT, WB);
  gemm_wq<<<(N + 63) / 64, 256, 0, stream>>>(hV, MT, WQb, N);
  neigh_aE<<<(N + 15) / 16, 256, 0, stream>>>(hE, mask, WQb, aEb, N);
  gemm_out<<<(N + 63) / 64, 256, 0, stream>>>(aEb, WB, out, N);
}

// Round 12
// 149.762 us; speedup vs baseline: 1.0904x; 1.0904x over previous
//
#include <hip/hip_runtime.h>
#include <hip/hip_bf16.h>

#define NEG_INF (-3.402823466e+38f)
#define SCALE 0.17677669529663689f  // 1/sqrt(32)

typedef __attribute__((ext_vector_type(8))) short bf16x8;
typedef __attribute__((ext_vector_type(4))) float f32x4;
typedef __attribute__((ext_vector_type(4))) unsigned short u16x4;
typedef __attribute__((ext_vector_type(4))) unsigned int u32x4;

__device__ __forceinline__ unsigned short f2bf(float f) {
  union { float f; unsigned u; } v; v.f = f;
  unsigned r = v.u + 0x7fffu + ((v.u >> 16) & 1u);
  return (unsigned short)(r >> 16);
}

// packed pair via compiler cvt_pk (RNE, matches f2bf)
__device__ __forceinline__ unsigned pack2(float lo, float hi) {
  __hip_bfloat162 h2 = __float22bfloat162_rn(make_float2(lo, hi));
  return *reinterpret_cast<unsigned*>(&h2);
}

__device__ __forceinline__ bf16x8 pack_bf8(const float* __restrict__ p) {
  float4 a = *(const float4*)p;
  float4 b = *(const float4*)(p + 4);
  u32x4 u;
  u[0] = pack2(a.x, a.y); u[1] = pack2(a.z, a.w);
  u[2] = pack2(b.x, b.y); u[3] = pack2(b.z, b.w);
  return __builtin_bit_cast(bf16x8, u);
}

// Precompute fused weight products (bf16):
//  MT[h][i][j] = M_h[j][i] = sum_d Wq[h*32+d][j] * Wk[h*32+d][i]
//  WB[o][h*128+i]          = sum_d Wo[o][h*32+d] * Wv[h*32+d][i]
__global__ __launch_bounds__(256) void fuse_weights(
    const float* __restrict__ wq, const float* __restrict__ wk,
    const float* __restrict__ wv, const float* __restrict__ wo,
    unsigned short* __restrict__ MT, unsigned short* __restrict__ WB) {
  const int w = (blockIdx.x * 256 + threadIdx.x) >> 6;  // wave id 0..255
  const int lane = threadIdx.x & 63;
  const int lr = lane & 15, lk = lane >> 4;
  const int h = w >> 6, t2 = w & 63, jt = t2 >> 3, it = t2 & 7;

  bf16x8 a, b;
#pragma unroll
  for (int j = 0; j < 8; ++j) {
    a[j] = (short)f2bf(wq[(h * 32 + lk * 8 + j) * 128 + jt * 16 + lr]);
    b[j] = (short)f2bf(wk[(h * 32 + lk * 8 + j) * 128 + it * 16 + lr]);
  }
  f32x4 c = (f32x4){0.f, 0.f, 0.f, 0.f};
  c = __builtin_amdgcn_mfma_f32_16x16x32_bf16(a, b, c, 0, 0, 0);
#pragma unroll
  for (int r = 0; r < 4; ++r)
    MT[h * 16384 + (it * 16 + lr) * 128 + jt * 16 + lk * 4 + r] = f2bf(c[r]);

  bf16x8 a2 = pack_bf8(wo + (jt * 16 + lr) * 128 + h * 32 + lk * 8);
  bf16x8 b2;
#pragma unroll
  for (int j = 0; j < 8; ++j)
    b2[j] = (short)f2bf(wv[(h * 32 + lk * 8 + j) * 128 + it * 16 + lr]);
  f32x4 c2 = (f32x4){0.f, 0.f, 0.f, 0.f};
  c2 = __builtin_amdgcn_mfma_f32_16x16x32_bf16(a2, b2, c2, 0, 0, 0);
#pragma unroll
  for (int r = 0; r < 4; ++r)
    WB[(size_t)(jt * 16 + lk * 4 + r) * 512 + h * 128 + it * 16 + lr] = f2bf(c2[r]);
}

// WQ[n][h*128+i] = sum_j hV[n][j] * M_h[j][i]; all 4 heads per block (h-loop).
__global__ __launch_bounds__(256) void gemm_wq(
    const float* __restrict__ X, const unsigned short* __restrict__ MT,
    unsigned short* __restrict__ WQb, int M) {
  __shared__ unsigned short Wl[128 * 136];
  const int wave = threadIdx.x >> 6, lane = threadIdx.x & 63;
  const int lr = lane & 15, lk = lane >> 4;
  const int row0 = blockIdx.x * 64 + wave * 16;
  const int arow = row0 + lr;

  bf16x8 af[4];
  if (arow < M) {
    const float* xr = X + (size_t)arow * 128;
#pragma unroll
    for (int kk = 0; kk < 4; ++kk) af[kk] = pack_bf8(xr + kk * 32 + lk * 8);
  } else {
#pragma unroll
    for (int kk = 0; kk < 4; ++kk) af[kk] = (bf16x8)(short)0;
  }

  for (int h = 0; h < 4; ++h) {
    __syncthreads();
    const unsigned short* Wsrc = MT + (size_t)h * 16384;
    for (int idx = threadIdx.x; idx < 2048; idx += 256) {
      int row = idx >> 4, col = (idx & 15) * 8;
      *(bf16x8*)&Wl[row * 136 + col] = *(const bf16x8*)(Wsrc + row * 128 + col);
    }
    __syncthreads();

    f32x4 acc[8];
#pragma unroll
    for (int ct = 0; ct < 8; ++ct) acc[ct] = (f32x4){0.f, 0.f, 0.f, 0.f};
#pragma unroll
    for (int kk = 0; kk < 4; ++kk)
#pragma unroll
      for (int ct = 0; ct < 8; ++ct) {
        bf16x8 b = *(const bf16x8*)&Wl[(ct * 16 + lr) * 136 + kk * 32 + lk * 8];
        acc[ct] = __builtin_amdgcn_mfma_f32_16x16x32_bf16(af[kk], b, acc[ct], 0, 0, 0);
      }

#pragma unroll
    for (int ct = 0; ct < 8; ++ct)
#pragma unroll
      for (int r = 0; r < 4; ++r) {
        int row = row0 + lk * 4 + r;
        if (row < M)
          WQb[(size_t)row * 512 + h * 128 + ct * 16 + lr] = f2bf(acc[ct][r]);
      }
  }
}

// Fused: logits -> softmax -> aE. 4 waves/block, one node per wave.
// E tile: A-fragments in registers (logits) + XOR-swizzled LDS copy, pitch 128.
// Swizzle: 8-elem block b of row k stored at b ^ (((k>>3)&3)<<1).
// Read (k=lk*8+j, i=ct*16+lr): block (ct*2+(lr>>3)) ^ (lk<<1), elem lr&7
//  -> 8 disjoint bank quartets, conflict-free.
__global__ __launch_bounds__(256, 4) void neigh_aE(
    const float* __restrict__ hE, const int* __restrict__ mask,
    const unsigned short* __restrict__ WQb, unsigned short* __restrict__ aEb,
    int N) {
  __shared__ unsigned short Elds[4][32 * 128];  // 8 KB per wave
  __shared__ unsigned short attL[4][128];       // att bf16 [h][k] per wave

  const int wave = threadIdx.x >> 6, lane = threadIdx.x & 63;
  const int lr = lane & 15, lk = lane >> 4;
  unsigned short* El = Elds[wave];
  unsigned short* at = attL[wave];
  const int n = blockIdx.x * 4 + wave;
  if (n >= N) return;

  // issue the big E loads first; small operands ride along
  const float* E = hE + (size_t)n * 4096;
  float4 raw[16];
#pragma unroll
  for (int q = 0; q < 8; ++q) {
    const float* p = E + ((q >> 2) * 16 + lr) * 128 + (q & 3) * 32 + lk * 8;
    raw[q * 2] = *(const float4*)p;
    raw[q * 2 + 1] = *(const float4*)(p + 4);
  }
  bf16x8 bq[4];
#pragma unroll
  for (int kk = 0; kk < 4; ++kk)
    bq[kk] = *(const bf16x8*)(WQb + (size_t)n * 512 + (lr & 3) * 128 + kk * 32 + lk * 8);
  const int4 m0 = *(const int4*)(mask + (size_t)n * 32 + lk * 4);
  const int4 m1 = *(const int4*)(mask + (size_t)n * 32 + 16 + lk * 4);

  // pack (cvt_pk) -> A-fragments (regs) + swizzled LDS copy
  bf16x8 af[2][4];
#pragma unroll
  for (int q = 0; q < 8; ++q) {
    float4 a = raw[q * 2], b = raw[q * 2 + 1];
    u32x4 u;
    u[0] = pack2(a.x, a.y); u[1] = pack2(a.z, a.w);
    u[2] = pack2(b.x, b.y); u[3] = pack2(b.z, b.w);
    bf16x8 t = __builtin_bit_cast(bf16x8, u);
    af[q >> 2][q & 3] = t;
    // row k = (q>>2)*16+lr ; block b = (q&3)*4+lk ; store at b ^ (((k>>3)&3)<<1)
    const int k = (q >> 2) * 16 + lr;
    const int bswz = ((q & 3) * 4 + lk) ^ ((((q >> 2) * 2 + (lr >> 3)) & 3) << 1);
    *(bf16x8*)&El[k * 128 + bswz * 8] = t;
  }

  // logits D[k][h]: lane holds k = rt*16 + lk*4 + r, col = head lr&3
  f32x4 c0 = (f32x4){0.f, 0.f, 0.f, 0.f};
  f32x4 c1 = (f32x4){0.f, 0.f, 0.f, 0.f};
#pragma unroll
  for (int kk = 0; kk < 4; ++kk) {
    c0 = __builtin_amdgcn_mfma_f32_16x16x32_bf16(af[0][kk], bq[kk], c0, 0, 0, 0);
    c1 = __builtin_amdgcn_mfma_f32_16x16x32_bf16(af[1][kk], bq[kk], c1, 0, 0, 0);
  }

  // masked softmax over k
  float l[2][4];
  l[0][0] = m0.x ? c0[0] * SCALE : NEG_INF;
  l[0][1] = m0.y ? c0[1] * SCALE : NEG_INF;
  l[0][2] = m0.z ? c0[2] * SCALE : NEG_INF;
  l[0][3] = m0.w ? c0[3] * SCALE : NEG_INF;
  l[1][0] = m1.x ? c1[0] * SCALE : NEG_INF;
  l[1][1] = m1.y ? c1[1] * SCALE : NEG_INF;
  l[1][2] = m1.z ? c1[2] * SCALE : NEG_INF;
  l[1][3] = m1.w ? c1[3] * SCALE : NEG_INF;

  float mx = l[0][0];
#pragma unroll
  for (int rt = 0; rt < 2; ++rt)
#pragma unroll
    for (int r = 0; r < 4; ++r) mx = fmaxf(mx, l[rt][r]);
  mx = fmaxf(mx, __shfl_xor(mx, 16, 64));
  mx = fmaxf(mx, __shfl_xor(mx, 32, 64));

  float e[2][4];
  float sum = 0.f;
#pragma unroll
  for (int rt = 0; rt < 2; ++rt)
#pragma unroll
    for (int r = 0; r < 4; ++r) { e[rt][r] = __expf(l[rt][r] - mx); sum += e[rt][r]; }
  sum += __shfl_xor(sum, 16, 64);
  sum += __shfl_xor(sum, 32, 64);
  const float inv = 1.0f / sum;

  if (lr < 4) {  // att[h=lr][k] bf16
    u16x4 p0, p1;
    p0[0] = f2bf(m0.x ? e[0][0] * inv : 0.f);
    p0[1] = f2bf(m0.y ? e[0][1] * inv : 0.f);
    p0[2] = f2bf(m0.z ? e[0][2] * inv : 0.f);
    p0[3] = f2bf(m0.w ? e[0][3] * inv : 0.f);
    p1[0] = f2bf(m1.x ? e[1][0] * inv : 0.f);
    p1[1] = f2bf(m1.y ? e[1][1] * inv : 0.f);
    p1[2] = f2bf(m1.z ? e[1][2] * inv : 0.f);
    p1[3] = f2bf(m1.w ? e[1][3] * inv : 0.f);
    *(u16x4*)&at[lr * 32 + lk * 4] = p0;
    *(u16x4*)&at[lr * 32 + 16 + lk * 4] = p1;
  }

  // aE: D[m][i] = sum_k att[m&3][k] E[k][ct*16+i]
  bf16x8 attA = *(const bf16x8*)&at[(lr & 3) * 32 + lk * 8];
  const int e0 = lr & 7;
#pragma unroll
  for (int ct = 0; ct < 8; ++ct) {
    const int blk = (ct * 2 + (lr >> 3)) ^ (lk << 1);
    bf16x8 bE;
#pragma unroll
    for (int j = 0; j < 8; ++j)
      bE[j] = (short)El[(lk * 8 + j) * 128 + blk * 8 + e0];
    f32x4 acc = (f32x4){0.f, 0.f, 0.f, 0.f};
    acc = __builtin_amdgcn_mfma_f32_16x16x32_bf16(attA, bE, acc, 0, 0, 0);
    // reg r holds head r (duplicated across lk); lane stores head = lk
    float v = (lk == 0) ? acc[0] : (lk == 1) ? acc[1] : (lk == 2) ? acc[2] : acc[3];
    aEb[(size_t)n * 512 + lk * 128 + ct * 16 + lr] = f2bf(v);
  }
}

// out[n][o] = sum_{h,i} aE[n][h*128+i] * WB[o][h*128+i]
__global__ __launch_bounds__(256) void gemm_out(
    const unsigned short* __restrict__ aEb, const unsigned short* __restrict__ WB,
    float* __restrict__ Y, int M) {
  __shared__ unsigned short Wl[128 * 136];
  const int wave = threadIdx.x >> 6, lane = threadIdx.x & 63;
  const int lr = lane & 15, lk = lane >> 4;
  const int row0 = blockIdx.x * 64 + wave * 16;
  const int arow = row0 + lr;

  f32x4 acc[8];
#pragma unroll
  for (int ct = 0; ct < 8; ++ct) acc[ct] = (f32x4){0.f, 0.f, 0.f, 0.f};

  for (int h = 0; h < 4; ++h) {
    __syncthreads();
    for (int idx = threadIdx.x; idx < 2048; idx += 256) {
      int row = idx >> 4, col = (idx & 15) * 8;
      *(bf16x8*)&Wl[row * 136 + col] = *(const bf16x8*)(WB + (size_t)row * 512 + h * 128 + col);
    }
    __syncthreads();

    bf16x8 af[4];
    if (arow < M) {
#pragma unroll
      for (int kk = 0; kk < 4; ++kk)
        af[kk] = *(const bf16x8*)(aEb + (size_t)arow * 512 + h * 128 + kk * 32 + lk * 8);
    } else {
#pragma unroll
      for (int kk = 0; kk < 4; ++kk) af[kk] = (bf16x8)(short)0;
    }
#pragma unroll
    for (int kk = 0; kk < 4; ++kk)
#pragma unroll
      for (int ct = 0; ct < 8; ++ct) {
        bf16x8 b = *(const bf16x8*)&Wl[(ct * 16 + lr) * 136 + kk * 32 + lk * 8];
        acc[ct] = __builtin_amdgcn_mfma_f32_16x16x32_bf16(af[kk], b, acc[ct], 0, 0, 0);
      }
  }

#pragma unroll
  for (int ct = 0; ct < 8; ++ct)
#pragma unroll
    for (int r = 0; r < 4; ++r) {
      int row = row0 + lk * 4 + r;
      if (row < M) Y[(size_t)row * 128 + ct * 16 + lr] = acc[ct][r];
    }
}

extern "C" void kernel_launch(void* const* d_in, const int* in_sizes, int n_in,
                              void* d_out, int out_size, void* d_ws, size_t ws_size,
                              hipStream_t stream) {
  const float* hV = (const float*)d_in[0];
  const float* hE = (const float*)d_in[1];
  const int* mask = (const int*)d_in[2];
  const float* Wq = (const float*)d_in[3];
  const float* Wk = (const float*)d_in[4];
  const float* Wv = (const float*)d_in[5];
  const float* Wo = (const float*)d_in[6];
  float* out = (float*)d_out;
  const int N = in_sizes[0] / 128;  // 30000

  char* ws = (char*)d_ws;
  unsigned short* MT = (unsigned short*)(ws);            // 4*128*128*2 = 128 KB
  unsigned short* WB = (unsigned short*)(ws + 131072);   // 128*512*2  = 128 KB
  unsigned short* WQb = (unsigned short*)(ws + 262144);               // N*512 bf16
  unsigned short* aEb = (unsigned short*)(ws + 262144 + (size_t)N * 1024);

  fuse_weights<<<64, 256, 0, stream>>>(Wq, Wk, Wv, Wo, MT, WB);
  gemm_wq<<<(N + 63) / 64, 256, 0, stream>>>(hV, MT, WQb, N);
  neigh_aE<<<(N + 3) / 4, 256, 0, stream>>>(hE, mask, WQb, aEb, N);
  gemm_out<<<(N + 63) / 64, 256, 0, stream>>>(aEb, WB, out, N);
}

// Round 13
// 124.121 us; speedup vs baseline: 1.3156x; 1.2066x over previous
//
#include <hip/hip_runtime.h>
#include <hip/hip_bf16.h>

#define NEG_INF (-3.402823466e+38f)
#define SCALE 0.17677669529663689f  // 1/sqrt(32)

typedef __attribute__((ext_vector_type(8))) short bf16x8;
typedef __attribute__((ext_vector_type(4))) float f32x4;
typedef __attribute__((ext_vector_type(4))) unsigned short u16x4;
typedef __attribute__((ext_vector_type(4))) unsigned int u32x4;

__device__ __forceinline__ unsigned short f2bf(float f) {
  union { float f; unsigned u; } v; v.f = f;
  unsigned r = v.u + 0x7fffu + ((v.u >> 16) & 1u);
  return (unsigned short)(r >> 16);
}

// packed pair via compiler cvt_pk (RNE, matches f2bf)
__device__ __forceinline__ unsigned pack2(float lo, float hi) {
  __hip_bfloat162 h2 = __float22bfloat162_rn(make_float2(lo, hi));
  return *reinterpret_cast<unsigned*>(&h2);
}

__device__ __forceinline__ bf16x8 pack_bf8(const float* __restrict__ p) {
  float4 a = *(const float4*)p;
  float4 b = *(const float4*)(p + 4);
  u32x4 u;
  u[0] = pack2(a.x, a.y); u[1] = pack2(a.z, a.w);
  u[2] = pack2(b.x, b.y); u[3] = pack2(b.z, b.w);
  return __builtin_bit_cast(bf16x8, u);
}

// Precompute fused weight products (bf16):
//  MT[h][i][j] = M_h[j][i] = sum_d Wq[h*32+d][j] * Wk[h*32+d][i]
//  WB[o][h*128+i]          = sum_d Wo[o][h*32+d] * Wv[h*32+d][i]
__global__ __launch_bounds__(256) void fuse_weights(
    const float* __restrict__ wq, const float* __restrict__ wk,
    const float* __restrict__ wv, const float* __restrict__ wo,
    unsigned short* __restrict__ MT, unsigned short* __restrict__ WB) {
  const int w = (blockIdx.x * 256 + threadIdx.x) >> 6;  // wave id 0..255
  const int lane = threadIdx.x & 63;
  const int lr = lane & 15, lk = lane >> 4;
  const int h = w >> 6, t2 = w & 63, jt = t2 >> 3, it = t2 & 7;

  bf16x8 a, b;
#pragma unroll
  for (int j = 0; j < 8; ++j) {
    a[j] = (short)f2bf(wq[(h * 32 + lk * 8 + j) * 128 + jt * 16 + lr]);
    b[j] = (short)f2bf(wk[(h * 32 + lk * 8 + j) * 128 + it * 16 + lr]);
  }
  f32x4 c = (f32x4){0.f, 0.f, 0.f, 0.f};
  c = __builtin_amdgcn_mfma_f32_16x16x32_bf16(a, b, c, 0, 0, 0);
#pragma unroll
  for (int r = 0; r < 4; ++r)
    MT[h * 16384 + (it * 16 + lr) * 128 + jt * 16 + lk * 4 + r] = f2bf(c[r]);

  bf16x8 a2 = pack_bf8(wo + (jt * 16 + lr) * 128 + h * 32 + lk * 8);
  bf16x8 b2;
#pragma unroll
  for (int j = 0; j < 8; ++j)
    b2[j] = (short)f2bf(wv[(h * 32 + lk * 8 + j) * 128 + it * 16 + lr]);
  f32x4 c2 = (f32x4){0.f, 0.f, 0.f, 0.f};
  c2 = __builtin_amdgcn_mfma_f32_16x16x32_bf16(a2, b2, c2, 0, 0, 0);
#pragma unroll
  for (int r = 0; r < 4; ++r)
    WB[(size_t)(jt * 16 + lk * 4 + r) * 512 + h * 128 + it * 16 + lr] = f2bf(c2[r]);
}

// WQ[n][h*128+i] = sum_j hV[n][j] * M_h[j][i]; all 4 heads per block (h-loop).
__global__ __launch_bounds__(256) void gemm_wq(
    const float* __restrict__ X, const unsigned short* __restrict__ MT,
    unsigned short* __restrict__ WQb, int M) {
  __shared__ unsigned short Wl[128 * 136];
  const int wave = threadIdx.x >> 6, lane = threadIdx.x & 63;
  const int lr = lane & 15, lk = lane >> 4;
  const int row0 = blockIdx.x * 64 + wave * 16;
  const int arow = row0 + lr;

  bf16x8 af[4];
  if (arow < M) {
    const float* xr = X + (size_t)arow * 128;
#pragma unroll
    for (int kk = 0; kk < 4; ++kk) af[kk] = pack_bf8(xr + kk * 32 + lk * 8);
  } else {
#pragma unroll
    for (int kk = 0; kk < 4; ++kk) af[kk] = (bf16x8)(short)0;
  }

  for (int h = 0; h < 4; ++h) {
    __syncthreads();
    const unsigned short* Wsrc = MT + (size_t)h * 16384;
    for (int idx = threadIdx.x; idx < 2048; idx += 256) {
      int row = idx >> 4, col = (idx & 15) * 8;
      *(bf16x8*)&Wl[row * 136 + col] = *(const bf16x8*)(Wsrc + row * 128 + col);
    }
    __syncthreads();

    f32x4 acc[8];
#pragma unroll
    for (int ct = 0; ct < 8; ++ct) acc[ct] = (f32x4){0.f, 0.f, 0.f, 0.f};
#pragma unroll
    for (int kk = 0; kk < 4; ++kk)
#pragma unroll
      for (int ct = 0; ct < 8; ++ct) {
        bf16x8 b = *(const bf16x8*)&Wl[(ct * 16 + lr) * 136 + kk * 32 + lk * 8];
        acc[ct] = __builtin_amdgcn_mfma_f32_16x16x32_bf16(af[kk], b, acc[ct], 0, 0, 0);
      }

#pragma unroll
    for (int ct = 0; ct < 8; ++ct)
#pragma unroll
      for (int r = 0; r < 4; ++r) {
        int row = row0 + lk * 4 + r;
        if (row < M)
          WQb[(size_t)row * 512 + h * 128 + ct * 16 + lr] = f2bf(acc[ct][r]);
      }
  }
}

// Fused: logits -> softmax -> aE. 4 waves/block, one node per wave.
// MASK-SKIP: E rows with mask[k]==0 are never used by the reference
// (logit -> NEG_INF, attend*mask -> 0), so their loads are skipped
// (~50% of h_E traffic). Masked rows are written as exact zeros into
// registers + LDS so no stale-NaN can leak through att=0 products.
// E tile: A-fragments in registers (logits) + XOR-swizzled LDS copy, pitch 128.
// Swizzle: 8-elem block b of row k stored at b ^ (((k>>3)&3)<<1).
// Read (k=lk*8+j, i=ct*16+lr): block (ct*2+(lr>>3)) ^ (lk<<1), elem lr&7
//  -> 8 disjoint bank quartets, conflict-free.
__global__ __launch_bounds__(256, 4) void neigh_aE(
    const float* __restrict__ hE, const int* __restrict__ mask,
    const unsigned short* __restrict__ WQb, unsigned short* __restrict__ aEb,
    int N) {
  __shared__ unsigned short Elds[4][32 * 128];  // 8 KB per wave
  __shared__ unsigned short attL[4][128];       // att bf16 [h][k] per wave

  const int wave = threadIdx.x >> 6, lane = threadIdx.x & 63;
  const int lr = lane & 15, lk = lane >> 4;
  unsigned short* El = Elds[wave];
  unsigned short* at = attL[wave];
  const int n = blockIdx.x * 4 + wave;
  if (n >= N) return;

  // masks first — they predicate the E loads
  const int4 m0 = *(const int4*)(mask + (size_t)n * 32 + lk * 4);
  const int4 m1 = *(const int4*)(mask + (size_t)n * 32 + 16 + lk * 4);
  const int mrow0 = mask[(size_t)n * 32 + lr];       // row lr
  const int mrow1 = mask[(size_t)n * 32 + 16 + lr];  // row 16+lr

  const float* E = hE + (size_t)n * 4096;
  const float4 z4 = make_float4(0.f, 0.f, 0.f, 0.f);
  float4 raw[16];
#pragma unroll
  for (int q = 0; q < 8; ++q) {
    const bool live = (q >> 2) ? (mrow1 != 0) : (mrow0 != 0);
    const float* p = E + ((q >> 2) * 16 + lr) * 128 + (q & 3) * 32 + lk * 8;
    if (live) {
      raw[q * 2] = *(const float4*)p;
      raw[q * 2 + 1] = *(const float4*)(p + 4);
    } else {
      raw[q * 2] = z4;
      raw[q * 2 + 1] = z4;
    }
  }
  bf16x8 bq[4];
#pragma unroll
  for (int kk = 0; kk < 4; ++kk)
    bq[kk] = *(const bf16x8*)(WQb + (size_t)n * 512 + (lr & 3) * 128 + kk * 32 + lk * 8);

  // pack (cvt_pk) -> A-fragments (regs) + swizzled LDS copy
  bf16x8 af[2][4];
#pragma unroll
  for (int q = 0; q < 8; ++q) {
    float4 a = raw[q * 2], b = raw[q * 2 + 1];
    u32x4 u;
    u[0] = pack2(a.x, a.y); u[1] = pack2(a.z, a.w);
    u[2] = pack2(b.x, b.y); u[3] = pack2(b.z, b.w);
    bf16x8 t = __builtin_bit_cast(bf16x8, u);
    af[q >> 2][q & 3] = t;
    // row k = (q>>2)*16+lr ; block b = (q&3)*4+lk ; store at b ^ (((k>>3)&3)<<1)
    const int k = (q >> 2) * 16 + lr;
    const int bswz = ((q & 3) * 4 + lk) ^ ((((q >> 2) * 2 + (lr >> 3)) & 3) << 1);
    *(bf16x8*)&El[k * 128 + bswz * 8] = t;
  }

  // logits D[k][h]: lane holds k = rt*16 + lk*4 + r, col = head lr&3
  f32x4 c0 = (f32x4){0.f, 0.f, 0.f, 0.f};
  f32x4 c1 = (f32x4){0.f, 0.f, 0.f, 0.f};
#pragma unroll
  for (int kk = 0; kk < 4; ++kk) {
    c0 = __builtin_amdgcn_mfma_f32_16x16x32_bf16(af[0][kk], bq[kk], c0, 0, 0, 0);
    c1 = __builtin_amdgcn_mfma_f32_16x16x32_bf16(af[1][kk], bq[kk], c1, 0, 0, 0);
  }

  // masked softmax over k
  float l[2][4];
  l[0][0] = m0.x ? c0[0] * SCALE : NEG_INF;
  l[0][1] = m0.y ? c0[1] * SCALE : NEG_INF;
  l[0][2] = m0.z ? c0[2] * SCALE : NEG_INF;
  l[0][3] = m0.w ? c0[3] * SCALE : NEG_INF;
  l[1][0] = m1.x ? c1[0] * SCALE : NEG_INF;
  l[1][1] = m1.y ? c1[1] * SCALE : NEG_INF;
  l[1][2] = m1.z ? c1[2] * SCALE : NEG_INF;
  l[1][3] = m1.w ? c1[3] * SCALE : NEG_INF;

  float mx = l[0][0];
#pragma unroll
  for (int rt = 0; rt < 2; ++rt)
#pragma unroll
    for (int r = 0; r < 4; ++r) mx = fmaxf(mx, l[rt][r]);
  mx = fmaxf(mx, __shfl_xor(mx, 16, 64));
  mx = fmaxf(mx, __shfl_xor(mx, 32, 64));

  float e[2][4];
  float sum = 0.f;
#pragma unroll
  for (int rt = 0; rt < 2; ++rt)
#pragma unroll
    for (int r = 0; r < 4; ++r) { e[rt][r] = __expf(l[rt][r] - mx); sum += e[rt][r]; }
  sum += __shfl_xor(sum, 16, 64);
  sum += __shfl_xor(sum, 32, 64);
  const float inv = 1.0f / sum;

  if (lr < 4) {  // att[h=lr][k] bf16
    u16x4 p0, p1;
    p0[0] = f2bf(m0.x ? e[0][0] * inv : 0.f);
    p0[1] = f2bf(m0.y ? e[0][1] * inv : 0.f);
    p0[2] = f2bf(m0.z ? e[0][2] * inv : 0.f);
    p0[3] = f2bf(m0.w ? e[0][3] * inv : 0.f);
    p1[0] = f2bf(m1.x ? e[1][0] * inv : 0.f);
    p1[1] = f2bf(m1.y ? e[1][1] * inv : 0.f);
    p1[2] = f2bf(m1.z ? e[1][2] * inv : 0.f);
    p1[3] = f2bf(m1.w ? e[1][3] * inv : 0.f);
    *(u16x4*)&at[lr * 32 + lk * 4] = p0;
    *(u16x4*)&at[lr * 32 + 16 + lk * 4] = p1;
  }

  // aE: D[m][i] = sum_k att[m&3][k] E[k][ct*16+i]
  bf16x8 attA = *(const bf16x8*)&at[(lr & 3) * 32 + lk * 8];
  const int e0 = lr & 7;
#pragma unroll
  for (int ct = 0; ct < 8; ++ct) {
    const int blk = (ct * 2 + (lr >> 3)) ^ (lk << 1);
    bf16x8 bE;
#pragma unroll
    for (int j = 0; j < 8; ++j)
      bE[j] = (short)El[(lk * 8 + j) * 128 + blk * 8 + e0];
    f32x4 acc = (f32x4){0.f, 0.f, 0.f, 0.f};
    acc = __builtin_amdgcn_mfma_f32_16x16x32_bf16(attA, bE, acc, 0, 0, 0);
    // reg r holds head r (duplicated across lk); lane stores head = lk
    float v = (lk == 0) ? acc[0] : (lk == 1) ? acc[1] : (lk == 2) ? acc[2] : acc[3];
    aEb[(size_t)n * 512 + lk * 128 + ct * 16 + lr] = f2bf(v);
  }
}

// out[n][o] = sum_{h,i} aE[n][h*128+i] * WB[o][h*128+i]
__global__ __launch_bounds__(256) void gemm_out(
    const unsigned short* __restrict__ aEb, const unsigned short* __restrict__ WB,
    float* __restrict__ Y, int M) {
  __shared__ unsigned short Wl[128 * 136];
  const int wave = threadIdx.x >> 6, lane = threadIdx.x & 63;
  const int lr = lane & 15, lk = lane >> 4;
  const int row0 = blockIdx.x * 64 + wave * 16;
  const int arow = row0 + lr;

  f32x4 acc[8];
#pragma unroll
  for (int ct = 0; ct < 8; ++ct) acc[ct] = (f32x4){0.f, 0.f, 0.f, 0.f};

  for (int h = 0; h < 4; ++h) {
    __syncthreads();
    for (int idx = threadIdx.x; idx < 2048; idx += 256) {
      int row = idx >> 4, col = (idx & 15) * 8;
      *(bf16x8*)&Wl[row * 136 + col] = *(const bf16x8*)(WB + (size_t)row * 512 + h * 128 + col);
    }
    __syncthreads();

    bf16x8 af[4];
    if (arow < M) {
#pragma unroll
      for (int kk = 0; kk < 4; ++kk)
        af[kk] = *(const bf16x8*)(aEb + (size_t)arow * 512 + h * 128 + kk * 32 + lk * 8);
    } else {
#pragma unroll
      for (int kk = 0; kk < 4; ++kk) af[kk] = (bf16x8)(short)0;
    }
#pragma unroll
    for (int kk = 0; kk < 4; ++kk)
#pragma unroll
      for (int ct = 0; ct < 8; ++ct) {
        bf16x8 b = *(const bf16x8*)&Wl[(ct * 16 + lr) * 136 + kk * 32 + lk * 8];
        acc[ct] = __builtin_amdgcn_mfma_f32_16x16x32_bf16(af[kk], b, acc[ct], 0, 0, 0);
      }
  }

#pragma unroll
  for (int ct = 0; ct < 8; ++ct)
#pragma unroll
    for (int r = 0; r < 4; ++r) {
      int row = row0 + lk * 4 + r;
      if (row < M) Y[(size_t)row * 128 + ct * 16 + lr] = acc[ct][r];
    }
}

extern "C" void kernel_launch(void* const* d_in, const int* in_sizes, int n_in,
                              void* d_out, int out_size, void* d_ws, size_t ws_size,
                              hipStream_t stream) {
  const float* hV = (const float*)d_in[0];
  const float* hE = (const float*)d_in[1];
  const int* mask = (const int*)d_in[2];
  const float* Wq = (const float*)d_in[3];
  const float* Wk = (const float*)d_in[4];
  const float* Wv = (const float*)d_in[5];
  const float* Wo = (const float*)d_in[6];
  float* out = (float*)d_out;
  const int N = in_sizes[0] / 128;  // 30000

  char* ws = (char*)d_ws;
  unsigned short* MT = (unsigned short*)(ws);            // 4*128*128*2 = 128 KB
  unsigned short* WB = (unsigned short*)(ws + 131072);   // 128*512*2  = 128 KB
  unsigned short* WQb = (unsigned short*)(ws + 262144);               // N*512 bf16
  unsigned short* aEb = (unsigned short*)(ws + 262144 + (size_t)N * 1024);

  fuse_weights<<<64, 256, 0, stream>>>(Wq, Wk, Wv, Wo, MT, WB);
  gemm_wq<<<(N + 63) / 64, 256, 0, stream>>>(hV, MT, WQb, N);
  neigh_aE<<<(N + 3) / 4, 256, 0, stream>>>(hE, mask, WQb, aEb, N);
  gemm_out<<<(N + 63) / 64, 256, 0, stream>>>(aEb, WB, out, N);
}